// Round 9
// baseline (364.709 us; speedup 1.0000x reference)
//
#include <hip/hip_runtime.h>
#include <hip/hip_bf16.h>
#include <math.h>

#define HDIM 128
#define BN_EPS 1e-5f
#define CHUNK 512
#define TM 32            // rows per layer-2 tile (smaller -> 8 blocks/CU)
#define LDA 132          // padded LDS row stride (floats)

// ---- helpers ----
__device__ __forceinline__ int eget(const void* ei, long long pos, int is64) {
    return is64 ? (int)((const long long*)ei)[pos] : ((const int*)ei)[pos];
}
__device__ __forceinline__ unsigned short f2bf(float f) {
    unsigned int u = __float_as_uint(f);
    u += 0x7fffu + ((u >> 16) & 1u);
    return (unsigned short)(u >> 16);
}
__device__ __forceinline__ unsigned int pack2bf(float lo, float hi) {
    return (unsigned int)f2bf(lo) | ((unsigned int)f2bf(hi) << 16);
}
__device__ __forceinline__ float bflo(unsigned int u) {
    return __uint_as_float(u << 16);
}
__device__ __forceinline__ float bfhi(unsigned int u) {
    return __uint_as_float(u & 0xffff0000u);
}

// Detect int64 vs int32 layout: int64 values < 2^31 have zero hi-words.
__global__ void k_detect(const int* ei32, int* flag) {
    if (threadIdx.x == 0) {
        int nz = 0;
        for (int k = 0; k < 64; ++k) nz += (ei32[2 * k + 1] != 0);
        *flag = (nz < 8) ? 1 : 0;   // 1 => int64
    }
}

__global__ void k_count(const void* ei, const int* flag, int* cnt, int E) {
    int e = blockIdx.x * blockDim.x + threadIdx.x;
    if (e < E) {
        int d = eget(ei, (long long)E + e, *flag);
        atomicAdd(&cnt[d], 1);
    }
}

__global__ void k_dis(const int* cnt, float* dis, int N) {
    int i = blockIdx.x * blockDim.x + threadIdx.x;
    if (i < N) dis[i] = rsqrtf((float)(cnt[i] + 1));
}

// ---- 3-kernel exclusive scan of cnt[N] -> rowptr[N+1] ----
__global__ void k_scan1(const int* cnt, int* bsum, int N) {
    __shared__ int s[256];
    int t = threadIdx.x;
    int i = blockIdx.x * CHUNK + t;
    int v = 0;
    if (i < N) v += cnt[i];
    if (i + 256 < N && t + 256 < CHUNK) v += cnt[i + 256];
    s[t] = v; __syncthreads();
    for (int o = 128; o > 0; o >>= 1) {
        if (t < o) s[t] += s[t + o];
        __syncthreads();
    }
    if (t == 0) bsum[blockIdx.x] = s[0];
}

__global__ void k_scan2(int* bsum, int nb) {
    __shared__ int s[512];
    int t = threadIdx.x;
    int carry = 0;
    for (int base = 0; base < nb; base += 512) {
        int i = base + t;
        int v = (i < nb) ? bsum[i] : 0;
        s[t] = v; __syncthreads();
        for (int o = 1; o < 512; o <<= 1) {
            int add = (t >= o) ? s[t - o] : 0;
            __syncthreads();
            s[t] += add;
            __syncthreads();
        }
        if (i < nb) bsum[i] = carry + s[t] - v;   // exclusive
        carry += s[511];
        __syncthreads();
    }
}

// also zeroes cnt (last reader) so fillcsr's fill[] starts at 0 w/o a memset
__global__ void k_scan3(int* cnt, const int* bsum, int* rowptr, int N) {
    __shared__ int s[CHUNK];
    int t = threadIdx.x;
    int i = blockIdx.x * CHUNK + t;
    int v = (i < N) ? cnt[i] : 0;
    s[t] = v; __syncthreads();
    for (int o = 1; o < CHUNK; o <<= 1) {
        int add = (t >= o) ? s[t - o] : 0;
        __syncthreads();
        s[t] += add;
        __syncthreads();
    }
    if (i < N) { rowptr[i] = bsum[blockIdx.x] + s[t] - v; cnt[i] = 0; }
    if (i == N - 1) rowptr[N] = bsum[blockIdx.x] + s[t];
}

// edge meta packed: emeta[pos] = {src, bits(norm)} — single 8B store
__global__ void k_fillcsr(const void* ei, const int* flag, const float* dis,
                          const int* rowptr, int* fill, int2* emeta, int E) {
    int e = blockIdx.x * blockDim.x + threadIdx.x;
    if (e < E) {
        int is64 = *flag;
        int s = eget(ei, e, is64);
        int d = eget(ei, (long long)E + e, is64);
        int pos = rowptr[d] + atomicAdd(&fill[d], 1);
        emeta[pos] = make_int2(s, __float_as_int(dis[s] * dis[d]));
    }
}

// pad x (N x 6) into xp (N x 8, zero tail) for aligned float4 gathers
__global__ void k_padx(const float* __restrict__ x, float* __restrict__ xp, int N) {
    int t = blockIdx.x * blockDim.x + threadIdx.x;
    if (t < N * 8) {
        int i = t >> 3, c = t & 7;
        xp[t] = (c < 6) ? x[i * 6 + c] : 0.f;
    }
}

// layer-1 aggregation of padded x (thread per node), edge loop unrolled x4
__global__ void k_gath_x(const float* __restrict__ xp, const int* __restrict__ rowptr,
                         const int2* __restrict__ emeta,
                         const float* __restrict__ dis, float* __restrict__ aggx, int N) {
    int i = blockIdx.x * blockDim.x + threadIdx.x;
    if (i >= N) return;
    float d = dis[i], d2 = d * d;
    float4 A = *(const float4*)&xp[i * 8];
    float2 B = *(const float2*)&xp[i * 8 + 4];
    float a0 = A.x * d2, a1 = A.y * d2, a2 = A.z * d2;
    float a3 = A.w * d2, a4 = B.x * d2, a5 = B.y * d2;
    int p = rowptr[i], pe = rowptr[i + 1];
    for (; p + 4 <= pe; p += 4) {
        int2 e0 = emeta[p], e1 = emeta[p + 1], e2 = emeta[p + 2], e3 = emeta[p + 3];
        float n0 = __int_as_float(e0.y), n1 = __int_as_float(e1.y);
        float n2 = __int_as_float(e2.y), n3 = __int_as_float(e3.y);
        float4 A0 = *(const float4*)&xp[e0.x * 8];
        float2 B0 = *(const float2*)&xp[e0.x * 8 + 4];
        float4 A1 = *(const float4*)&xp[e1.x * 8];
        float2 B1 = *(const float2*)&xp[e1.x * 8 + 4];
        float4 A2 = *(const float4*)&xp[e2.x * 8];
        float2 B2 = *(const float2*)&xp[e2.x * 8 + 4];
        float4 A3 = *(const float4*)&xp[e3.x * 8];
        float2 B3 = *(const float2*)&xp[e3.x * 8 + 4];
        a0 += (A0.x * n0 + A1.x * n1) + (A2.x * n2 + A3.x * n3);
        a1 += (A0.y * n0 + A1.y * n1) + (A2.y * n2 + A3.y * n3);
        a2 += (A0.z * n0 + A1.z * n1) + (A2.z * n2 + A3.z * n3);
        a3 += (A0.w * n0 + A1.w * n1) + (A2.w * n2 + A3.w * n3);
        a4 += (B0.x * n0 + B1.x * n1) + (B2.x * n2 + B3.x * n3);
        a5 += (B0.y * n0 + B1.y * n1) + (B2.y * n2 + B3.y * n3);
    }
    for (; p < pe; ++p) {
        int2 e0 = emeta[p];
        float n0 = __int_as_float(e0.y);
        float4 A0 = *(const float4*)&xp[e0.x * 8];
        float2 B0 = *(const float2*)&xp[e0.x * 8 + 4];
        a0 += A0.x * n0; a1 += A0.y * n0; a2 += A0.z * n0;
        a3 += A0.w * n0; a4 += B0.x * n0; a5 += B0.y * n0;
    }
    aggx[i * 6 + 0] = a0; aggx[i * 6 + 1] = a1; aggx[i * 6 + 2] = a2;
    aggx[i * 6 + 3] = a3; aggx[i * 6 + 4] = a4; aggx[i * 6 + 5] = a5;
}

// m1[i][j] = dot(aggx[i], W1[:,j]) + b1[j]  (K=6) -> bf16, fused f32 col sums
__global__ void k_gemm6(const float* __restrict__ aggx, const float* __restrict__ W1,
                        const float* __restrict__ b1, unsigned short* __restrict__ out,
                        float* __restrict__ S, int N) {
    __shared__ float w[6 * HDIM];
    __shared__ float bb[HDIM];
    __shared__ float sh1[256], sh2[256];
    for (int t = threadIdx.x; t < 6 * HDIM; t += blockDim.x) w[t] = W1[t];
    if (threadIdx.x < HDIM) bb[threadIdx.x] = b1[threadIdx.x];
    __syncthreads();
    int j = threadIdx.x & (HDIM - 1);
    int sub = threadIdx.x >> 7;
    float s1 = 0.f, s2 = 0.f;
    for (long long i = blockIdx.x * 2 + sub; i < N; i += (long long)gridDim.x * 2) {
        const float* r = &aggx[i * 6];
        float acc = bb[j];
        acc += r[0] * w[0 * HDIM + j];
        acc += r[1] * w[1 * HDIM + j];
        acc += r[2] * w[2 * HDIM + j];
        acc += r[3] * w[3 * HDIM + j];
        acc += r[4] * w[4 * HDIM + j];
        acc += r[5] * w[5 * HDIM + j];
        out[i * HDIM + j] = f2bf(acc);
        s1 += acc; s2 += acc * acc;
    }
    sh1[threadIdx.x] = s1; sh2[threadIdx.x] = s2;
    __syncthreads();
    if (threadIdx.x < HDIM) {
        atomicAdd(&S[j], sh1[j] + sh1[j + HDIM]);
        atomicAdd(&S[HDIM + j], sh2[j] + sh2[j + HDIM]);
    }
}

// ===== fused layer 2: per-block BN1 params -> gather(m1 bf16, BN1+ReLU) ->
//       LDS tile (TM=32) -> GEMM 128x128 -> m2 bf16 + f32 column-sum epilogue.
//       256 threads, 8 blocks/CU for inter-block latency hiding.
//       Gather: round-7 proven 32-lane x uint2 shape, unroll x4, named scalars. =====
__global__ __launch_bounds__(256, 8)
void k_agg_gemm(const unsigned short* __restrict__ m1,
                const float* __restrict__ S1, const float* __restrict__ g1,
                const float* __restrict__ be1, float invN,
                const int* __restrict__ rowptr, const int2* __restrict__ emeta,
                const float* __restrict__ dis,
                const float* __restrict__ W, const float* __restrict__ b,
                unsigned short* __restrict__ out, float* __restrict__ S,
                int* __restrict__ ticket, int ntiles, int N) {
    __shared__ float At[TM * LDA];          // 16.9 KB
    __shared__ float Pp[256];
    __shared__ int s_tile;
    const int tid = threadIdx.x;

    // per-block BN1 param compute (replaces k_bnparams launch)
    if (tid < HDIM) {
        float mu = S1[tid] * invN;
        float var = S1[HDIM + tid] * invN - mu * mu;
        float al = g1[tid] * rsqrtf(var + BN_EPS);
        Pp[tid] = al;
        Pp[HDIM + tid] = be1[tid] - mu * al;
    }
    __syncthreads();

    // gather-phase constants: 32 lanes x 4 cols, 8 node-groups
    const int gl = tid & 31;
    const int gq = tid >> 5;                // 0..7
    const int c4 = gl * 4;
    const float4 pa = *(const float4*)&Pp[c4];
    const float4 pb = *(const float4*)&Pp[HDIM + c4];

    // GEMM-phase constants
    const int cg = tid & 31;
    const int rg = tid >> 5;                // 0..7
    const int c0 = cg * 4;
    const int r0 = rg * 4;
    const float4 bv = *(const float4*)&b[c0];

    for (;;) {
        if (tid == 0) s_tile = atomicAdd(ticket, 1);
        __syncthreads();
        const int tile = s_tile;
        if (tile >= ntiles) return;
        const long long i0 = (long long)tile * TM;

        // ---- gather phase (edge loop unrolled x4: 4 row-loads in flight) ----
        for (int nn = gq; nn < TM; nn += 8) {
            long long i = i0 + nn;
            float a0 = 0.f, a1 = 0.f, a2 = 0.f, a3 = 0.f;
            if (i < N) {
                float d = dis[i], d2 = d * d;
                uint2 us = *(const uint2*)&m1[i * HDIM + c4];
                a0 = fmaxf(fmaf(pa.x, bflo(us.x), pb.x), 0.f) * d2;
                a1 = fmaxf(fmaf(pa.y, bfhi(us.x), pb.y), 0.f) * d2;
                a2 = fmaxf(fmaf(pa.z, bflo(us.y), pb.z), 0.f) * d2;
                a3 = fmaxf(fmaf(pa.w, bfhi(us.y), pb.w), 0.f) * d2;
                int p = rowptr[i], pe = rowptr[i + 1];
                for (; p + 4 <= pe; p += 4) {
                    int2 eA = emeta[p],     eB = emeta[p + 1];
                    int2 eC = emeta[p + 2], eD = emeta[p + 3];
                    float nA = __int_as_float(eA.y), nB = __int_as_float(eB.y);
                    float nC = __int_as_float(eC.y), nD = __int_as_float(eD.y);
                    uint2 uA = *(const uint2*)&m1[(long long)eA.x * HDIM + c4];
                    uint2 uB = *(const uint2*)&m1[(long long)eB.x * HDIM + c4];
                    uint2 uC = *(const uint2*)&m1[(long long)eC.x * HDIM + c4];
                    uint2 uD = *(const uint2*)&m1[(long long)eD.x * HDIM + c4];
                    a0 += (fmaxf(fmaf(pa.x, bflo(uA.x), pb.x), 0.f) * nA
                         + fmaxf(fmaf(pa.x, bflo(uB.x), pb.x), 0.f) * nB)
                        + (fmaxf(fmaf(pa.x, bflo(uC.x), pb.x), 0.f) * nC
                         + fmaxf(fmaf(pa.x, bflo(uD.x), pb.x), 0.f) * nD);
                    a1 += (fmaxf(fmaf(pa.y, bfhi(uA.x), pb.y), 0.f) * nA
                         + fmaxf(fmaf(pa.y, bfhi(uB.x), pb.y), 0.f) * nB)
                        + (fmaxf(fmaf(pa.y, bfhi(uC.x), pb.y), 0.f) * nC
                         + fmaxf(fmaf(pa.y, bfhi(uD.x), pb.y), 0.f) * nD);
                    a2 += (fmaxf(fmaf(pa.z, bflo(uA.y), pb.z), 0.f) * nA
                         + fmaxf(fmaf(pa.z, bflo(uB.y), pb.z), 0.f) * nB)
                        + (fmaxf(fmaf(pa.z, bflo(uC.y), pb.z), 0.f) * nC
                         + fmaxf(fmaf(pa.z, bflo(uD.y), pb.z), 0.f) * nD);
                    a3 += (fmaxf(fmaf(pa.w, bfhi(uA.y), pb.w), 0.f) * nA
                         + fmaxf(fmaf(pa.w, bfhi(uB.y), pb.w), 0.f) * nB)
                        + (fmaxf(fmaf(pa.w, bfhi(uC.y), pb.w), 0.f) * nC
                         + fmaxf(fmaf(pa.w, bfhi(uD.y), pb.w), 0.f) * nD);
                }
                if (p + 2 <= pe) {
                    int2 eA = emeta[p], eB = emeta[p + 1];
                    float nA = __int_as_float(eA.y), nB = __int_as_float(eB.y);
                    uint2 uA = *(const uint2*)&m1[(long long)eA.x * HDIM + c4];
                    uint2 uB = *(const uint2*)&m1[(long long)eB.x * HDIM + c4];
                    a0 += fmaxf(fmaf(pa.x, bflo(uA.x), pb.x), 0.f) * nA
                        + fmaxf(fmaf(pa.x, bflo(uB.x), pb.x), 0.f) * nB;
                    a1 += fmaxf(fmaf(pa.y, bfhi(uA.x), pb.y), 0.f) * nA
                        + fmaxf(fmaf(pa.y, bfhi(uB.x), pb.y), 0.f) * nB;
                    a2 += fmaxf(fmaf(pa.z, bflo(uA.y), pb.z), 0.f) * nA
                        + fmaxf(fmaf(pa.z, bflo(uB.y), pb.z), 0.f) * nB;
                    a3 += fmaxf(fmaf(pa.w, bfhi(uA.y), pb.w), 0.f) * nA
                        + fmaxf(fmaf(pa.w, bfhi(uB.y), pb.w), 0.f) * nB;
                    p += 2;
                }
                if (p < pe) {
                    int2 eA = emeta[p];
                    float nA = __int_as_float(eA.y);
                    uint2 uA = *(const uint2*)&m1[(long long)eA.x * HDIM + c4];
                    a0 += fmaxf(fmaf(pa.x, bflo(uA.x), pb.x), 0.f) * nA;
                    a1 += fmaxf(fmaf(pa.y, bfhi(uA.x), pb.y), 0.f) * nA;
                    a2 += fmaxf(fmaf(pa.z, bflo(uA.y), pb.z), 0.f) * nA;
                    a3 += fmaxf(fmaf(pa.w, bfhi(uA.y), pb.w), 0.f) * nA;
                }
            }
            *(float4*)&At[nn * LDA + c4] = make_float4(a0, a1, a2, a3);
        }
        __syncthreads();

        // ---- GEMM phase: 4x4 register block per thread (32 rows) ----
        float acc[4][4];
        #pragma unroll
        for (int rr = 0; rr < 4; ++rr) {
            acc[rr][0] = bv.x; acc[rr][1] = bv.y; acc[rr][2] = bv.z; acc[rr][3] = bv.w;
        }
        for (int k = 0; k < HDIM; k += 4) {
            const float4 w0 = *(const float4*)&W[(k + 0) * HDIM + c0];
            const float4 w1 = *(const float4*)&W[(k + 1) * HDIM + c0];
            const float4 w2 = *(const float4*)&W[(k + 2) * HDIM + c0];
            const float4 w3 = *(const float4*)&W[(k + 3) * HDIM + c0];
            #pragma unroll
            for (int rr = 0; rr < 4; ++rr) {
                const float4 av = *(const float4*)&At[(r0 + rr) * LDA + k];
                acc[rr][0] = fmaf(av.x, w0.x, acc[rr][0]);
                acc[rr][1] = fmaf(av.x, w0.y, acc[rr][1]);
                acc[rr][2] = fmaf(av.x, w0.z, acc[rr][2]);
                acc[rr][3] = fmaf(av.x, w0.w, acc[rr][3]);
                acc[rr][0] = fmaf(av.y, w1.x, acc[rr][0]);
                acc[rr][1] = fmaf(av.y, w1.y, acc[rr][1]);
                acc[rr][2] = fmaf(av.y, w1.z, acc[rr][2]);
                acc[rr][3] = fmaf(av.y, w1.w, acc[rr][3]);
                acc[rr][0] = fmaf(av.z, w2.x, acc[rr][0]);
                acc[rr][1] = fmaf(av.z, w2.y, acc[rr][1]);
                acc[rr][2] = fmaf(av.z, w2.z, acc[rr][2]);
                acc[rr][3] = fmaf(av.z, w2.w, acc[rr][3]);
                acc[rr][0] = fmaf(av.w, w3.x, acc[rr][0]);
                acc[rr][1] = fmaf(av.w, w3.y, acc[rr][1]);
                acc[rr][2] = fmaf(av.w, w3.z, acc[rr][2]);
                acc[rr][3] = fmaf(av.w, w3.w, acc[rr][3]);
            }
        }

        // store m2 as bf16 + per-thread exact f32 column partials
        float cs1[4] = {0.f, 0.f, 0.f, 0.f};
        float cs2[4] = {0.f, 0.f, 0.f, 0.f};
        #pragma unroll
        for (int rr = 0; rr < 4; ++rr) {
            long long i = i0 + r0 + rr;
            if (i < N) {
                uint2 o;
                o.x = pack2bf(acc[rr][0], acc[rr][1]);
                o.y = pack2bf(acc[rr][2], acc[rr][3]);
                *(uint2*)&out[i * HDIM + c0] = o;
                #pragma unroll
                for (int cc = 0; cc < 4; ++cc) {
                    float v = acc[rr][cc];
                    cs1[cc] += v; cs2[cc] += v * v;
                }
            }
        }
        __syncthreads();        // At free; reuse as reduction scratch
        #pragma unroll
        for (int cc = 0; cc < 4; ++cc) {
            At[rg * HDIM + c0 + cc]        = cs1[cc];
            At[1024 + rg * HDIM + c0 + cc] = cs2[cc];
        }
        __syncthreads();
        {
            int j = tid & (HDIM - 1);
            int which = tid >> 7;               // 0 = sum, 1 = sumsq
            const float* bp = &At[which * 1024 + j];
            float s = 0.f;
            #pragma unroll
            for (int g = 0; g < 8; ++g) s += bp[g * HDIM];
            atomicAdd(&S[which * HDIM + j], s);
        }
        __syncthreads();        // protect At/s_tile before next iteration
    }
}

// m3[i] = dot(relu(BN2(m2[i])), W3), m2 bf16; per-block BN2 params; persistent
__global__ void k_gemv2(const unsigned short* __restrict__ m2,
                        const float* __restrict__ S2, const float* __restrict__ g2,
                        const float* __restrict__ be2, float invN,
                        const float* __restrict__ W3, float* __restrict__ m3, int N) {
    __shared__ float Pp[256];
    int tid = threadIdx.x;
    if (tid < HDIM) {
        float mu = S2[tid] * invN;
        float var = S2[HDIM + tid] * invN - mu * mu;
        float al = g2[tid] * rsqrtf(var + BN_EPS);
        Pp[tid] = al;
        Pp[HDIM + tid] = be2[tid] - mu * al;
    }
    __syncthreads();
    int l = tid & 31;
    int c4 = l * 4;
    float4 pa = *(const float4*)&Pp[c4];
    float4 pb = *(const float4*)&Pp[HDIM + c4];
    float4 w  = *(const float4*)&W3[c4];
    for (long long row = blockIdx.x * 8 + (tid >> 5); row < N;
         row += (long long)gridDim.x * 8) {
        uint2 v = *(const uint2*)&m2[row * HDIM + c4];
        float s = fmaxf(fmaf(pa.x, bflo(v.x), pb.x), 0.f) * w.x
                + fmaxf(fmaf(pa.y, bfhi(v.x), pb.y), 0.f) * w.y
                + fmaxf(fmaf(pa.z, bflo(v.y), pb.z), 0.f) * w.z
                + fmaxf(fmaf(pa.w, bfhi(v.y), pb.w), 0.f) * w.w;
        for (int o = 16; o > 0; o >>= 1) s += __shfl_down(s, o, 32);
        if (l == 0) m3[row] = s;
    }
}

// layer-3 gather + bias + sigmoid
__global__ void k_gath_o(const float* __restrict__ m3, const int* __restrict__ rowptr,
                         const int2* __restrict__ emeta,
                         const float* __restrict__ dis, const float* __restrict__ b3,
                         float* __restrict__ out, int N) {
    int i = blockIdx.x * blockDim.x + threadIdx.x;
    if (i < N) {
        float d = dis[i];
        float acc = m3[i] * d * d;
        int p = rowptr[i], pe = rowptr[i + 1];
        for (; p + 4 <= pe; p += 4) {
            int2 e0 = emeta[p], e1 = emeta[p + 1], e2 = emeta[p + 2], e3 = emeta[p + 3];
            float v0 = m3[e0.x] * __int_as_float(e0.y);
            float v1 = m3[e1.x] * __int_as_float(e1.y);
            float v2 = m3[e2.x] * __int_as_float(e2.y);
            float v3 = m3[e3.x] * __int_as_float(e3.y);
            acc += (v0 + v1) + (v2 + v3);
        }
        for (; p < pe; ++p) {
            int2 e0 = emeta[p];
            acc += m3[e0.x] * __int_as_float(e0.y);
        }
        acc += b3[0];
        out[i] = 1.f / (1.f + expf(-acc));
    }
}

extern "C" void kernel_launch(void* const* d_in, const int* in_sizes, int n_in,
                              void* d_out, int out_size, void* d_ws, size_t ws_size,
                              hipStream_t stream) {
    const float* x  = (const float*)d_in[0];
    const void*  ei = d_in[1];
    const float* W1 = (const float*)d_in[2];
    const float* b1 = (const float*)d_in[3];
    const float* W2 = (const float*)d_in[4];
    const float* b2 = (const float*)d_in[5];
    const float* W3 = (const float*)d_in[6];
    const float* b3 = (const float*)d_in[7];
    const float* g1 = (const float*)d_in[8];
    const float* be1 = (const float*)d_in[9];
    const float* g2 = (const float*)d_in[10];
    const float* be2 = (const float*)d_in[11];

    const int N = in_sizes[0] / 6;
    const int E = in_sizes[1] / 2;
    const float invN = 1.0f / (float)N;

    // ---- workspace layout (float units, 16B-aligned chunks) ----
    // [flag/ticket 16][S1 256][S2 256] contiguous -> one memset covers all
    float* ws = (float*)d_ws;
    long long off = 0;
    auto pad4 = [](long long v) { return (v + 3) & ~3LL; };
    int*   flag   = (int*)ws;                 off += 16;   // [0]=flag, [1]=ticket
    int*   ticket = (int*)ws + 1;
    float* S1     = ws + off;                 off += 256;
    float* S2     = ws + off;                 off += 256;
    float* dis    = ws + off;                 off = pad4(off + N);
    int*   cnt    = (int*)(ws + off);         off = pad4(off + N);
    int*   rowptr = (int*)(ws + off);         off = pad4(off + N + 16);
    int2*  emeta  = (int2*)(ws + off);        off = pad4(off + (long long)2 * E);
    int*   bsum   = (int*)(ws + off);         off += 512;
    float* xp     = ws + off;                 off = pad4(off + (long long)8 * N);
    float* aggx   = ws + off;                 off = pad4(off + (long long)6 * N);
    float* m3     = ws + off;                 off = pad4(off + N);
    // m1, m2: N x 128 bf16 = 64N floats each
    unsigned short* m1 = (unsigned short*)(ws + off); off = pad4(off + (long long)64 * N);
    unsigned short* m2 = (unsigned short*)(ws + off); off = pad4(off + (long long)64 * N);

    const int T = 256;
    const int bN  = (N + T - 1) / T;
    const int bE  = (E + T - 1) / T;
    const int nchunk = (N + CHUNK - 1) / CHUNK;
    const int ntiles = (N + TM - 1) / TM;

    // ---- CSR build + norm ----
    hipMemsetAsync(ws, 0, 528 * sizeof(float), stream);   // flag+ticket+S1+S2
    hipMemsetAsync(cnt, 0, (size_t)N * sizeof(int), stream);
    k_detect<<<1, 64, 0, stream>>>((const int*)ei, flag);
    k_count<<<bE, T, 0, stream>>>(ei, flag, cnt, E);
    k_dis<<<bN, T, 0, stream>>>(cnt, dis, N);
    k_scan1<<<nchunk, 256, 0, stream>>>(cnt, bsum, N);
    k_scan2<<<1, 512, 0, stream>>>(bsum, nchunk);
    k_scan3<<<nchunk, CHUNK, 0, stream>>>(cnt, bsum, rowptr, N);  // zeroes cnt
    k_fillcsr<<<bE, T, 0, stream>>>(ei, flag, dis, rowptr, cnt, emeta, E);

    // ---- layer 1: pad x -> gather -> GEMM 6->128 (bf16 out, +colsum) ----
    k_padx<<<(N * 8 + T - 1) / T, T, 0, stream>>>(x, xp, N);
    k_gath_x<<<bN, T, 0, stream>>>(xp, rowptr, emeta, dis, aggx, N);
    k_gemm6<<<512, T, 0, stream>>>(aggx, W1, b1, m1, S1, N);

    // ---- layer 2 fused: BN1 params in-kernel -> gather -> GEMM -> bf16 m2 ----
    k_agg_gemm<<<2048, 256, 0, stream>>>(m1, S1, g1, be1, invN,
                                         rowptr, emeta, dis,
                                         W2, b2, m2, S2, ticket, ntiles, N);

    // ---- layer 3: BN2 params in-kernel; 128->1; gather scalars + sigmoid ----
    k_gemv2<<<1024, T, 0, stream>>>(m2, S2, g2, be2, invN, W3, m3, N);
    k_gath_o<<<bN, T, 0, stream>>>(m3, rowptr, emeta, dis, b3, (float*)d_out, N);
}

// Round 10
// 265.711 us; speedup vs baseline: 1.3726x; 1.3726x over previous
//
#include <hip/hip_runtime.h>
#include <hip/hip_bf16.h>
#include <math.h>

#define HDIM 128
#define BN_EPS 1e-5f
#define CHUNK 512
#define TM 64            // rows per layer-2 tile (round-7 proven config)
#define LDA 132          // padded LDS row stride (floats)

// ---- helpers ----
__device__ __forceinline__ int eget(const void* ei, long long pos, int is64) {
    return is64 ? (int)((const long long*)ei)[pos] : ((const int*)ei)[pos];
}
__device__ __forceinline__ unsigned short f2bf(float f) {
    unsigned int u = __float_as_uint(f);
    u += 0x7fffu + ((u >> 16) & 1u);
    return (unsigned short)(u >> 16);
}
__device__ __forceinline__ unsigned int pack2bf(float lo, float hi) {
    return (unsigned int)f2bf(lo) | ((unsigned int)f2bf(hi) << 16);
}
__device__ __forceinline__ float bflo(unsigned int u) {
    return __uint_as_float(u << 16);
}
__device__ __forceinline__ float bfhi(unsigned int u) {
    return __uint_as_float(u & 0xffff0000u);
}

// per-block int64-vs-int32 detect: 64 threads sample hi-words, LDS-reduce
__device__ __forceinline__ int block_is64(const void* ei) {
    __shared__ int snz;
    if (threadIdx.x == 0) snz = 0;
    __syncthreads();
    if (threadIdx.x < 64 && ((const int*)ei)[2 * threadIdx.x + 1] != 0)
        atomicAdd(&snz, 1);
    __syncthreads();
    return (snz < 8) ? 1 : 0;
}

// count in-degree; fused: pad x -> xp (N x 8), convert W2 -> bf16
__global__ void k_count(const void* ei, int* cnt, int E,
                        const float* __restrict__ x, float* __restrict__ xp,
                        long long n8,
                        const float* __restrict__ W2f,
                        unsigned short* __restrict__ w2h) {
    int is64 = block_is64(ei);
    long long e = (long long)blockIdx.x * blockDim.x + threadIdx.x;
    long long stride = (long long)gridDim.x * blockDim.x;
    if (e < E) {
        int d = eget(ei, (long long)E + e, is64);
        atomicAdd(&cnt[d], 1);
    }
    for (long long t = e; t < n8; t += stride) {
        int i = (int)(t >> 3), c = (int)(t & 7);
        xp[t] = (c < 6) ? x[i * 6 + c] : 0.f;
    }
    for (long long t = e; t < HDIM * HDIM; t += stride)
        w2h[t] = f2bf(W2f[t]);
}

// ---- 3-kernel exclusive scan of cnt[N] -> rowptr[N+1]; scan1 fuses dis ----
__global__ void k_scan1(const int* cnt, int* bsum, float* __restrict__ dis, int N) {
    __shared__ int s[256];
    int t = threadIdx.x;
    int i = blockIdx.x * CHUNK + t;
    int v = 0;
    if (i < N) {
        int c = cnt[i]; v += c;
        dis[i] = rsqrtf((float)(c + 1));
    }
    if (i + 256 < N && t + 256 < CHUNK) {
        int c = cnt[i + 256]; v += c;
        dis[i + 256] = rsqrtf((float)(c + 1));
    }
    s[t] = v; __syncthreads();
    for (int o = 128; o > 0; o >>= 1) {
        if (t < o) s[t] += s[t + o];
        __syncthreads();
    }
    if (t == 0) bsum[blockIdx.x] = s[0];
}

__global__ void k_scan2(int* bsum, int nb) {
    __shared__ int s[512];
    int t = threadIdx.x;
    int carry = 0;
    for (int base = 0; base < nb; base += 512) {
        int i = base + t;
        int v = (i < nb) ? bsum[i] : 0;
        s[t] = v; __syncthreads();
        for (int o = 1; o < 512; o <<= 1) {
            int add = (t >= o) ? s[t - o] : 0;
            __syncthreads();
            s[t] += add;
            __syncthreads();
        }
        if (i < nb) bsum[i] = carry + s[t] - v;   // exclusive
        carry += s[511];
        __syncthreads();
    }
}

// also zeroes cnt (last reader) so fillcsr's fill[] starts at 0 w/o a memset
__global__ void k_scan3(int* cnt, const int* bsum, int* rowptr, int N) {
    __shared__ int s[CHUNK];
    int t = threadIdx.x;
    int i = blockIdx.x * CHUNK + t;
    int v = (i < N) ? cnt[i] : 0;
    s[t] = v; __syncthreads();
    for (int o = 1; o < CHUNK; o <<= 1) {
        int add = (t >= o) ? s[t - o] : 0;
        __syncthreads();
        s[t] += add;
        __syncthreads();
    }
    if (i < N) { rowptr[i] = bsum[blockIdx.x] + s[t] - v; cnt[i] = 0; }
    if (i == N - 1) rowptr[N] = bsum[blockIdx.x] + s[t];
}

// edge meta packed: emeta[pos] = {src, bits(norm)} — single 8B store
__global__ void k_fillcsr(const void* ei, const float* dis,
                          const int* rowptr, int* fill, int2* emeta, int E) {
    int is64 = block_is64(ei);
    int e = blockIdx.x * blockDim.x + threadIdx.x;
    if (e < E) {
        int s = eget(ei, e, is64);
        int d = eget(ei, (long long)E + e, is64);
        int pos = rowptr[d] + atomicAdd(&fill[d], 1);
        emeta[pos] = make_int2(s, __float_as_int(dis[s] * dis[d]));
    }
}

// layer-1 aggregation of padded x (thread per node), edge loop unrolled x4
__global__ void k_gath_x(const float* __restrict__ xp, const int* __restrict__ rowptr,
                         const int2* __restrict__ emeta,
                         const float* __restrict__ dis, float* __restrict__ aggx, int N) {
    int i = blockIdx.x * blockDim.x + threadIdx.x;
    if (i >= N) return;
    float d = dis[i], d2 = d * d;
    float4 A = *(const float4*)&xp[i * 8];
    float2 B = *(const float2*)&xp[i * 8 + 4];
    float a0 = A.x * d2, a1 = A.y * d2, a2 = A.z * d2;
    float a3 = A.w * d2, a4 = B.x * d2, a5 = B.y * d2;
    int p = rowptr[i], pe = rowptr[i + 1];
    for (; p + 4 <= pe; p += 4) {
        int2 e0 = emeta[p], e1 = emeta[p + 1], e2 = emeta[p + 2], e3 = emeta[p + 3];
        float n0 = __int_as_float(e0.y), n1 = __int_as_float(e1.y);
        float n2 = __int_as_float(e2.y), n3 = __int_as_float(e3.y);
        float4 A0 = *(const float4*)&xp[e0.x * 8];
        float2 B0 = *(const float2*)&xp[e0.x * 8 + 4];
        float4 A1 = *(const float4*)&xp[e1.x * 8];
        float2 B1 = *(const float2*)&xp[e1.x * 8 + 4];
        float4 A2 = *(const float4*)&xp[e2.x * 8];
        float2 B2 = *(const float2*)&xp[e2.x * 8 + 4];
        float4 A3 = *(const float4*)&xp[e3.x * 8];
        float2 B3 = *(const float2*)&xp[e3.x * 8 + 4];
        a0 += (A0.x * n0 + A1.x * n1) + (A2.x * n2 + A3.x * n3);
        a1 += (A0.y * n0 + A1.y * n1) + (A2.y * n2 + A3.y * n3);
        a2 += (A0.z * n0 + A1.z * n1) + (A2.z * n2 + A3.z * n3);
        a3 += (A0.w * n0 + A1.w * n1) + (A2.w * n2 + A3.w * n3);
        a4 += (B0.x * n0 + B1.x * n1) + (B2.x * n2 + B3.x * n3);
        a5 += (B0.y * n0 + B1.y * n1) + (B2.y * n2 + B3.y * n3);
    }
    for (; p < pe; ++p) {
        int2 e0 = emeta[p];
        float n0 = __int_as_float(e0.y);
        float4 A0 = *(const float4*)&xp[e0.x * 8];
        float2 B0 = *(const float2*)&xp[e0.x * 8 + 4];
        a0 += A0.x * n0; a1 += A0.y * n0; a2 += A0.z * n0;
        a3 += A0.w * n0; a4 += B0.x * n0; a5 += B0.y * n0;
    }
    aggx[i * 6 + 0] = a0; aggx[i * 6 + 1] = a1; aggx[i * 6 + 2] = a2;
    aggx[i * 6 + 3] = a3; aggx[i * 6 + 4] = a4; aggx[i * 6 + 5] = a5;
}

// m1[i][j] = dot(aggx[i], W1[:,j]) + b1[j]  (K=6) -> bf16, fused f32 col sums
__global__ void k_gemm6(const float* __restrict__ aggx, const float* __restrict__ W1,
                        const float* __restrict__ b1, unsigned short* __restrict__ out,
                        float* __restrict__ S, int N) {
    __shared__ float w[6 * HDIM];
    __shared__ float bb[HDIM];
    __shared__ float sh1[256], sh2[256];
    for (int t = threadIdx.x; t < 6 * HDIM; t += blockDim.x) w[t] = W1[t];
    if (threadIdx.x < HDIM) bb[threadIdx.x] = b1[threadIdx.x];
    __syncthreads();
    int j = threadIdx.x & (HDIM - 1);
    int sub = threadIdx.x >> 7;
    float s1 = 0.f, s2 = 0.f;
    for (long long i = blockIdx.x * 2 + sub; i < N; i += (long long)gridDim.x * 2) {
        const float* r = &aggx[i * 6];
        float acc = bb[j];
        acc += r[0] * w[0 * HDIM + j];
        acc += r[1] * w[1 * HDIM + j];
        acc += r[2] * w[2 * HDIM + j];
        acc += r[3] * w[3 * HDIM + j];
        acc += r[4] * w[4 * HDIM + j];
        acc += r[5] * w[5 * HDIM + j];
        out[i * HDIM + j] = f2bf(acc);
        s1 += acc; s2 += acc * acc;
    }
    sh1[threadIdx.x] = s1; sh2[threadIdx.x] = s2;
    __syncthreads();
    if (threadIdx.x < HDIM) {
        atomicAdd(&S[j], sh1[j] + sh1[j + HDIM]);
        atomicAdd(&S[HDIM + j], sh2[j] + sh2[j + HDIM]);
    }
}

// ===== fused layer 2 (round-7 proven structure): per-block BN1 params ->
//       gather(m1 bf16, BN1+ReLU) -> LDS tile -> GEMM 128x128 (W2 bf16) ->
//       m2 bf16 + exact f32 column-sum epilogue. Persistent, ticketed. =====
__global__ __launch_bounds__(512, 6)
void k_agg_gemm(const unsigned short* __restrict__ m1,
                const float* __restrict__ S1, const float* __restrict__ g1,
                const float* __restrict__ be1, float invN,
                const int* __restrict__ rowptr, const int2* __restrict__ emeta,
                const float* __restrict__ dis,
                const unsigned short* __restrict__ W, const float* __restrict__ b,
                unsigned short* __restrict__ out, float* __restrict__ S,
                int* __restrict__ ticket, int ntiles, int N) {
    __shared__ float At[TM * LDA];
    __shared__ float Pp[256];
    __shared__ int s_tile;
    const int tid = threadIdx.x;

    // per-block BN1 param compute (replaces k_bnparams launch)
    if (tid < HDIM) {
        float mu = S1[tid] * invN;
        float var = S1[HDIM + tid] * invN - mu * mu;
        float al = g1[tid] * rsqrtf(var + BN_EPS);
        Pp[tid] = al;
        Pp[HDIM + tid] = be1[tid] - mu * al;
    }
    __syncthreads();

    // gather-phase constants: 32 lanes x 4 cols, 16 node-groups
    const int gl = tid & 31;
    const int gq = tid >> 5;                // 0..15
    const int c4 = gl * 4;
    const float4 pa = *(const float4*)&Pp[c4];
    const float4 pb = *(const float4*)&Pp[HDIM + c4];

    // GEMM-phase constants
    const int cg = tid & 31;
    const int rg = tid >> 5;                // 0..15
    const int c0 = cg * 4;
    const int r0 = rg * 4;
    const float4 bv = *(const float4*)&b[c0];

    for (;;) {
        if (tid == 0) s_tile = atomicAdd(ticket, 1);
        __syncthreads();
        const int tile = s_tile;
        if (tile >= ntiles) return;
        const long long i0 = (long long)tile * TM;

        // ---- gather phase (edge loop unrolled x4: 4 row-loads in flight) ----
        for (int nn = gq; nn < TM; nn += 16) {
            long long i = i0 + nn;
            float a0 = 0.f, a1 = 0.f, a2 = 0.f, a3 = 0.f;
            if (i < N) {
                float d = dis[i], d2 = d * d;
                uint2 us = *(const uint2*)&m1[i * HDIM + c4];
                a0 = fmaxf(fmaf(pa.x, bflo(us.x), pb.x), 0.f) * d2;
                a1 = fmaxf(fmaf(pa.y, bfhi(us.x), pb.y), 0.f) * d2;
                a2 = fmaxf(fmaf(pa.z, bflo(us.y), pb.z), 0.f) * d2;
                a3 = fmaxf(fmaf(pa.w, bfhi(us.y), pb.w), 0.f) * d2;
                int p = rowptr[i], pe = rowptr[i + 1];
                for (; p + 4 <= pe; p += 4) {
                    int2 eA = emeta[p],     eB = emeta[p + 1];
                    int2 eC = emeta[p + 2], eD = emeta[p + 3];
                    float nA = __int_as_float(eA.y), nB = __int_as_float(eB.y);
                    float nC = __int_as_float(eC.y), nD = __int_as_float(eD.y);
                    uint2 uA = *(const uint2*)&m1[(long long)eA.x * HDIM + c4];
                    uint2 uB = *(const uint2*)&m1[(long long)eB.x * HDIM + c4];
                    uint2 uC = *(const uint2*)&m1[(long long)eC.x * HDIM + c4];
                    uint2 uD = *(const uint2*)&m1[(long long)eD.x * HDIM + c4];
                    a0 += (fmaxf(fmaf(pa.x, bflo(uA.x), pb.x), 0.f) * nA
                         + fmaxf(fmaf(pa.x, bflo(uB.x), pb.x), 0.f) * nB)
                        + (fmaxf(fmaf(pa.x, bflo(uC.x), pb.x), 0.f) * nC
                         + fmaxf(fmaf(pa.x, bflo(uD.x), pb.x), 0.f) * nD);
                    a1 += (fmaxf(fmaf(pa.y, bfhi(uA.x), pb.y), 0.f) * nA
                         + fmaxf(fmaf(pa.y, bfhi(uB.x), pb.y), 0.f) * nB)
                        + (fmaxf(fmaf(pa.y, bfhi(uC.x), pb.y), 0.f) * nC
                         + fmaxf(fmaf(pa.y, bfhi(uD.x), pb.y), 0.f) * nD);
                    a2 += (fmaxf(fmaf(pa.z, bflo(uA.y), pb.z), 0.f) * nA
                         + fmaxf(fmaf(pa.z, bflo(uB.y), pb.z), 0.f) * nB)
                        + (fmaxf(fmaf(pa.z, bflo(uC.y), pb.z), 0.f) * nC
                         + fmaxf(fmaf(pa.z, bflo(uD.y), pb.z), 0.f) * nD);
                    a3 += (fmaxf(fmaf(pa.w, bfhi(uA.y), pb.w), 0.f) * nA
                         + fmaxf(fmaf(pa.w, bfhi(uB.y), pb.w), 0.f) * nB)
                        + (fmaxf(fmaf(pa.w, bfhi(uC.y), pb.w), 0.f) * nC
                         + fmaxf(fmaf(pa.w, bfhi(uD.y), pb.w), 0.f) * nD);
                }
                if (p + 2 <= pe) {
                    int2 eA = emeta[p], eB = emeta[p + 1];
                    float nA = __int_as_float(eA.y), nB = __int_as_float(eB.y);
                    uint2 uA = *(const uint2*)&m1[(long long)eA.x * HDIM + c4];
                    uint2 uB = *(const uint2*)&m1[(long long)eB.x * HDIM + c4];
                    a0 += fmaxf(fmaf(pa.x, bflo(uA.x), pb.x), 0.f) * nA
                        + fmaxf(fmaf(pa.x, bflo(uB.x), pb.x), 0.f) * nB;
                    a1 += fmaxf(fmaf(pa.y, bfhi(uA.x), pb.y), 0.f) * nA
                        + fmaxf(fmaf(pa.y, bfhi(uB.x), pb.y), 0.f) * nB;
                    a2 += fmaxf(fmaf(pa.z, bflo(uA.y), pb.z), 0.f) * nA
                        + fmaxf(fmaf(pa.z, bflo(uB.y), pb.z), 0.f) * nB;
                    a3 += fmaxf(fmaf(pa.w, bfhi(uA.y), pb.w), 0.f) * nA
                        + fmaxf(fmaf(pa.w, bfhi(uB.y), pb.w), 0.f) * nB;
                    p += 2;
                }
                if (p < pe) {
                    int2 eA = emeta[p];
                    float nA = __int_as_float(eA.y);
                    uint2 uA = *(const uint2*)&m1[(long long)eA.x * HDIM + c4];
                    a0 += fmaxf(fmaf(pa.x, bflo(uA.x), pb.x), 0.f) * nA;
                    a1 += fmaxf(fmaf(pa.y, bfhi(uA.x), pb.y), 0.f) * nA;
                    a2 += fmaxf(fmaf(pa.z, bflo(uA.y), pb.z), 0.f) * nA;
                    a3 += fmaxf(fmaf(pa.w, bfhi(uA.y), pb.w), 0.f) * nA;
                }
            }
            *(float4*)&At[nn * LDA + c4] = make_float4(a0, a1, a2, a3);
        }
        __syncthreads();

        // ---- GEMM phase: 4x4 register block per thread, W2 in bf16 ----
        float acc[4][4];
        #pragma unroll
        for (int rr = 0; rr < 4; ++rr) {
            acc[rr][0] = bv.x; acc[rr][1] = bv.y; acc[rr][2] = bv.z; acc[rr][3] = bv.w;
        }
        for (int k = 0; k < HDIM; k += 4) {
            const uint2 q0 = *(const uint2*)&W[(k + 0) * HDIM + c0];
            const uint2 q1 = *(const uint2*)&W[(k + 1) * HDIM + c0];
            const uint2 q2 = *(const uint2*)&W[(k + 2) * HDIM + c0];
            const uint2 q3 = *(const uint2*)&W[(k + 3) * HDIM + c0];
            const float w00 = bflo(q0.x), w01 = bfhi(q0.x), w02 = bflo(q0.y), w03 = bfhi(q0.y);
            const float w10 = bflo(q1.x), w11 = bfhi(q1.x), w12 = bflo(q1.y), w13 = bfhi(q1.y);
            const float w20 = bflo(q2.x), w21 = bfhi(q2.x), w22 = bflo(q2.y), w23 = bfhi(q2.y);
            const float w30 = bflo(q3.x), w31 = bfhi(q3.x), w32 = bflo(q3.y), w33 = bfhi(q3.y);
            #pragma unroll
            for (int rr = 0; rr < 4; ++rr) {
                const float4 av = *(const float4*)&At[(r0 + rr) * LDA + k];
                acc[rr][0] = fmaf(av.x, w00, acc[rr][0]);
                acc[rr][1] = fmaf(av.x, w01, acc[rr][1]);
                acc[rr][2] = fmaf(av.x, w02, acc[rr][2]);
                acc[rr][3] = fmaf(av.x, w03, acc[rr][3]);
                acc[rr][0] = fmaf(av.y, w10, acc[rr][0]);
                acc[rr][1] = fmaf(av.y, w11, acc[rr][1]);
                acc[rr][2] = fmaf(av.y, w12, acc[rr][2]);
                acc[rr][3] = fmaf(av.y, w13, acc[rr][3]);
                acc[rr][0] = fmaf(av.z, w20, acc[rr][0]);
                acc[rr][1] = fmaf(av.z, w21, acc[rr][1]);
                acc[rr][2] = fmaf(av.z, w22, acc[rr][2]);
                acc[rr][3] = fmaf(av.z, w23, acc[rr][3]);
                acc[rr][0] = fmaf(av.w, w30, acc[rr][0]);
                acc[rr][1] = fmaf(av.w, w31, acc[rr][1]);
                acc[rr][2] = fmaf(av.w, w32, acc[rr][2]);
                acc[rr][3] = fmaf(av.w, w33, acc[rr][3]);
            }
        }

        // store m2 as bf16 + per-thread exact f32 column partials
        float cs1[4] = {0.f, 0.f, 0.f, 0.f};
        float cs2[4] = {0.f, 0.f, 0.f, 0.f};
        #pragma unroll
        for (int rr = 0; rr < 4; ++rr) {
            long long i = i0 + r0 + rr;
            if (i < N) {
                uint2 o;
                o.x = pack2bf(acc[rr][0], acc[rr][1]);
                o.y = pack2bf(acc[rr][2], acc[rr][3]);
                *(uint2*)&out[i * HDIM + c0] = o;
                #pragma unroll
                for (int cc = 0; cc < 4; ++cc) {
                    float v = acc[rr][cc];
                    cs1[cc] += v; cs2[cc] += v * v;
                }
            }
        }
        __syncthreads();        // At free; reuse as reduction scratch
        #pragma unroll
        for (int cc = 0; cc < 4; ++cc) {
            At[rg * HDIM + c0 + cc]        = cs1[cc];
            At[2048 + rg * HDIM + c0 + cc] = cs2[cc];
        }
        __syncthreads();
        if (tid < 256) {
            int j = tid & (HDIM - 1);
            int which = tid >> 7;
            const float* bp = &At[which * 2048 + j];
            float s = 0.f;
            #pragma unroll
            for (int g = 0; g < 16; ++g) s += bp[g * HDIM];
            atomicAdd(&S[which * HDIM + j], s);
        }
        __syncthreads();        // protect At/s_tile before next iteration
    }
}

// m3[i] = dot(relu(BN2(m2[i])), W3), m2 bf16; per-block BN2 params; persistent
__global__ void k_gemv2(const unsigned short* __restrict__ m2,
                        const float* __restrict__ S2, const float* __restrict__ g2,
                        const float* __restrict__ be2, float invN,
                        const float* __restrict__ W3, float* __restrict__ m3, int N) {
    __shared__ float Pp[256];
    int tid = threadIdx.x;
    if (tid < HDIM) {
        float mu = S2[tid] * invN;
        float var = S2[HDIM + tid] * invN - mu * mu;
        float al = g2[tid] * rsqrtf(var + BN_EPS);
        Pp[tid] = al;
        Pp[HDIM + tid] = be2[tid] - mu * al;
    }
    __syncthreads();
    int l = tid & 31;
    int c4 = l * 4;
    float4 pa = *(const float4*)&Pp[c4];
    float4 pb = *(const float4*)&Pp[HDIM + c4];
    float4 w  = *(const float4*)&W3[c4];
    for (long long row = blockIdx.x * 8 + (tid >> 5); row < N;
         row += (long long)gridDim.x * 8) {
        uint2 v = *(const uint2*)&m2[row * HDIM + c4];
        float s = fmaxf(fmaf(pa.x, bflo(v.x), pb.x), 0.f) * w.x
                + fmaxf(fmaf(pa.y, bfhi(v.x), pb.y), 0.f) * w.y
                + fmaxf(fmaf(pa.z, bflo(v.y), pb.z), 0.f) * w.z
                + fmaxf(fmaf(pa.w, bfhi(v.y), pb.w), 0.f) * w.w;
        for (int o = 16; o > 0; o >>= 1) s += __shfl_down(s, o, 32);
        if (l == 0) m3[row] = s;
    }
}

// layer-3 gather + bias + sigmoid
__global__ void k_gath_o(const float* __restrict__ m3, const int* __restrict__ rowptr,
                         const int2* __restrict__ emeta,
                         const float* __restrict__ dis, const float* __restrict__ b3,
                         float* __restrict__ out, int N) {
    int i = blockIdx.x * blockDim.x + threadIdx.x;
    if (i < N) {
        float d = dis[i];
        float acc = m3[i] * d * d;
        int p = rowptr[i], pe = rowptr[i + 1];
        for (; p + 4 <= pe; p += 4) {
            int2 e0 = emeta[p], e1 = emeta[p + 1], e2 = emeta[p + 2], e3 = emeta[p + 3];
            float v0 = m3[e0.x] * __int_as_float(e0.y);
            float v1 = m3[e1.x] * __int_as_float(e1.y);
            float v2 = m3[e2.x] * __int_as_float(e2.y);
            float v3 = m3[e3.x] * __int_as_float(e3.y);
            acc += (v0 + v1) + (v2 + v3);
        }
        for (; p < pe; ++p) {
            int2 e0 = emeta[p];
            acc += m3[e0.x] * __int_as_float(e0.y);
        }
        acc += b3[0];
        out[i] = 1.f / (1.f + expf(-acc));
    }
}

extern "C" void kernel_launch(void* const* d_in, const int* in_sizes, int n_in,
                              void* d_out, int out_size, void* d_ws, size_t ws_size,
                              hipStream_t stream) {
    const float* x  = (const float*)d_in[0];
    const void*  ei = d_in[1];
    const float* W1 = (const float*)d_in[2];
    const float* b1 = (const float*)d_in[3];
    const float* W2 = (const float*)d_in[4];
    const float* b2 = (const float*)d_in[5];
    const float* W3 = (const float*)d_in[6];
    const float* b3 = (const float*)d_in[7];
    const float* g1 = (const float*)d_in[8];
    const float* be1 = (const float*)d_in[9];
    const float* g2 = (const float*)d_in[10];
    const float* be2 = (const float*)d_in[11];

    const int N = in_sizes[0] / 6;
    const int E = in_sizes[1] / 2;
    const float invN = 1.0f / (float)N;

    // ---- workspace layout (float units, 16B-aligned chunks) ----
    float* ws = (float*)d_ws;
    long long off = 0;
    auto pad4 = [](long long v) { return (v + 3) & ~3LL; };
    int*   flag   = (int*)ws;                 off += 16;   // [1]=ticket
    int*   ticket = (int*)ws + 1;
    float* S1     = ws + off;                 off += 256;
    float* S2     = ws + off;                 off += 256;
    float* dis    = ws + off;                 off = pad4(off + N);
    int*   cnt    = (int*)(ws + off);         off = pad4(off + N);
    int*   rowptr = (int*)(ws + off);         off = pad4(off + N + 16);
    int2*  emeta  = (int2*)(ws + off);        off = pad4(off + (long long)2 * E);
    int*   bsum   = (int*)(ws + off);         off += 512;
    unsigned short* w2h = (unsigned short*)(ws + off); off += HDIM * HDIM / 2;
    float* xp     = ws + off;                 off = pad4(off + (long long)8 * N);
    float* aggx   = ws + off;                 off = pad4(off + (long long)6 * N);
    float* m3     = ws + off;                 off = pad4(off + N);
    // m1, m2: N x 128 bf16 = 64N floats each
    unsigned short* m1 = (unsigned short*)(ws + off); off = pad4(off + (long long)64 * N);
    unsigned short* m2 = (unsigned short*)(ws + off); off = pad4(off + (long long)64 * N);

    const int T = 256;
    const int bN  = (N + T - 1) / T;
    const int bE  = (E + T - 1) / T;
    const int nchunk = (N + CHUNK - 1) / CHUNK;
    const int ntiles = (N + TM - 1) / TM;

    // ---- CSR build + norm (detect folded per-block; dis folded into scan1;
    //      padx + W2->bf16 folded into count) ----
    hipMemsetAsync(ws, 0, 528 * sizeof(float), stream);   // flag+ticket+S1+S2
    hipMemsetAsync(cnt, 0, (size_t)N * sizeof(int), stream);
    k_count<<<bE, T, 0, stream>>>(ei, cnt, E, x, xp, (long long)8 * N, W2, w2h);
    k_scan1<<<nchunk, 256, 0, stream>>>(cnt, bsum, dis, N);
    k_scan2<<<1, 512, 0, stream>>>(bsum, nchunk);
    k_scan3<<<nchunk, CHUNK, 0, stream>>>(cnt, bsum, rowptr, N);  // zeroes cnt
    k_fillcsr<<<bE, T, 0, stream>>>(ei, dis, rowptr, cnt, emeta, E);

    // ---- layer 1: gather -> GEMM 6->128 (bf16 out, +colsum) ----
    k_gath_x<<<bN, T, 0, stream>>>(xp, rowptr, emeta, dis, aggx, N);
    k_gemm6<<<512, T, 0, stream>>>(aggx, W1, b1, m1, S1, N);

    // ---- layer 2 fused: BN1 params in-kernel -> gather -> GEMM -> bf16 m2 ----
    k_agg_gemm<<<1024, 512, 0, stream>>>(m1, S1, g1, be1, invN,
                                         rowptr, emeta, dis,
                                         w2h, b2, m2, S2, ticket, ntiles, N);

    // ---- layer 3: BN2 params in-kernel; 128->1; gather scalars + sigmoid ----
    k_gemv2<<<1024, T, 0, stream>>>(m2, S2, g2, be2, invN, W3, m3, N);
    k_gath_o<<<bN, T, 0, stream>>>(m3, rowptr, emeta, dis, b3, (float*)d_out, N);
}